// Round 13
// baseline (232.252 us; speedup 1.0000x reference)
//
#include <hip/hip_runtime.h>
#include <stdint.h>

// SpatialHyperedgeMP: out = ((inc + head) @ cur) / rowsum(inc + head)
//   head_ij = (inc_ij > 0) / sqrt(cnt_i),  cnt_i = #positives in row i
// Decomposition (single fused pass over inc):
//   out[i] = (inc@cur + invs_i * (mask@cur)) * rdeg_i
//   invs_i = 1/sqrt(cnt_i),  rdeg_i = 1/(s1_i + sqrt(cnt_i))
//
// R13 = R11 with the wave->tile decomposition changed 8x(32x32) -> (2x4)x(16x64).
//   R11 post-mortem: DS top pipe (~1920 cyc/CU-pair) from 8 waves reading
//   IDENTICAL A+M frags. R12 (mask in-reg) put 96 VALU on the MFMA dependent
//   path -> worse. The 16x64 wave tile halves A/M frag reads per wave (2+2
//   b128) and amortizes each over 2x the MFMA work: DS ~1150 < MFMA 1242
//   (MFMA becomes top pipe). B frags duplicated 2x across row-groups (L2 has
//   headroom). B regs rotate per-kh (2 sets x 4 frags = 32 VGPR, R11-level)
//   to stay under the 128-VGPR cap (R8 spill lesson).
//   Everything else byte-identical to R11 (best: 167 us).
//
// ws usage: 8MB B chunks only.

#define NROWS 8192
#define DDIM  512

typedef float f32x4 __attribute__((ext_vector_type(4)));
typedef short s16x8 __attribute__((ext_vector_type(8)));

__device__ __forceinline__ unsigned short f2bf(float f) {
  union { float f; unsigned int u; } c; c.f = f;
  unsigned int u = c.u;
  unsigned int r = u + 0x7FFFu + ((u >> 16) & 1u);
  return (unsigned short)(r >> 16);
}

// ---------------- kernel 1: B prep (cur -> bf16 chunked-transposed) ----------------
// chunk layout: nt(2) x kt(128): 32KB chunk = [kg=8][nn=256][e=8] bf16
__global__ __launch_bounds__(256) void bprep_kernel(const float* __restrict__ cur,
                                                    unsigned char* __restrict__ bws) {
  int idx = blockIdx.x * 256 + threadIdx.x;  // 0..524287
  int n = idx & 511;
  int kg9 = idx >> 9;  // 0..1023
  int kt = kg9 >> 3;
  int kg = kg9 & 7;
  int k0 = kt * 64 + kg * 8;
  union { unsigned short h[8]; uint4 q; } u;
#pragma unroll
  for (int e = 0; e < 8; ++e)
    u.h[e] = f2bf(cur[(size_t)(k0 + e) * DDIM + n]);
  int nt = n >> 8, nn = n & 255;
  size_t off = ((size_t)(nt * 128 + kt) << 15) + ((size_t)kg << 12) + ((size_t)nn << 4);
  *(uint4*)(bws + off) = u.q;
}

// ---------------- kernel 2: fused stats + dual-GEMM ----------------
// BM=32 BN=256 BK=64, 512 thr = 8 waves as (2 row-groups x 4 col-groups),
// wave tile 16x64. LDS (16.2KB): {A 4KB + M 4KB} x dbuf; stats reuse buf0.

#define FENCE() __builtin_amdgcn_sched_barrier(0)
#define BARRIER() __builtin_amdgcn_s_barrier()
#define WAITLGKM() asm volatile("s_waitcnt lgkmcnt(0)" ::: "memory")
#define MFMA_ __builtin_amdgcn_mfma_f32_16x16x32_bf16

__global__ __launch_bounds__(512, 4) void gemm_kernel(const float* __restrict__ inc,
                                                      const unsigned char* __restrict__ bws,
                                                      float* __restrict__ out) {
  __shared__ __align__(16) unsigned char smem[16512];
  unsigned char* const buf0 = smem;          // A @0, M @+4096
  unsigned char* const buf1 = smem + 8192;

  const int tid = threadIdx.x;
  const int lane = tid & 63;
  const int wv = tid >> 6;       // 0..7
  const int wr = wv >> 2;        // row-group 0..1 (16 rows)
  const int wc = wv & 3;         // col-group 0..3 (64 cols)
  const int r = lane & 15;
  const int q = lane >> 4;       // 0..3

  const int id = blockIdx.x;     // 0..511
  const int nt = (id & 7) >> 2;  // XCD half -> fixed 4MB B chunk per XCD L2
  const int mt = (id >> 3) * 4 + (id & 3);   // 0..255; partners id,id^4 adjacent
  const int brow = mt * 32;

  // ---- A staging ownership: thread -> (row sm, float4-slot sp) ----
  const int sm = tid >> 4;       // 0..31
  const int sp = tid & 15;       // 0..15 (k = sp*4..sp*4+3)
  const int kgw = sp >> 1, half = sp & 1;
  const float4* gAr = (const float4*)(inc + (size_t)(brow + sm) * NROWS) + sp;
  const int aWr = (kgw << 9) + ((sm ^ kgw) << 4) + (half << 3);

  // ---- A/M frag LDS offsets: frag(kh): kg=kh*4+q, row=wr*16+r ----
  int aOff[2];
#pragma unroll
  for (int kh = 0; kh < 2; ++kh) {
    int kg = kh * 4 + q;
    int row = wr * 16 + r;
    aOff[kh] = (kg << 9) + ((row ^ kg) << 4);
  }

  // ---- B frag ws offsets (within 32KB kt-chunk): cols wc*64+cg*16+r ----
  const unsigned char* gB = bws + ((size_t)(nt * 128) << 15);
  int bOff[2][4];  // [kh][cg]
#pragma unroll
  for (int kh = 0; kh < 2; ++kh)
#pragma unroll
    for (int cg = 0; cg < 4; ++cg)
      bOff[kh][cg] = ((kh * 4 + q) << 12) + ((wc * 64 + cg * 16 + r) << 4);

  f32x4 acc1[4], acc2[4];
#pragma unroll
  for (int b = 0; b < 4; ++b) {
    acc1[b] = (f32x4){0.f, 0.f, 0.f, 0.f};
    acc2[b] = (f32x4){0.f, 0.f, 0.f, 0.f};
  }

  double s1 = 0.0;
  int cnt = 0;
  float4 x, y;
  s16x8 bA[4], bB[4];   // per-kh B reg sets: bA = kh0, bB = kh1 (fixed roles)

#define ISSUE_A(d, KT) do { d = gAr[(KT) * 16]; } while (0)

#define LOADB(BS, KT, KH) do {                                                            \
    const unsigned char* _g = gB + ((size_t)(KT) << 15);                                  \
    BS[0] = *(const s16x8*)(_g + bOff[KH][0]);                                            \
    BS[1] = *(const s16x8*)(_g + bOff[KH][1]);                                            \
    BS[2] = *(const s16x8*)(_g + bOff[KH][2]);                                            \
    BS[3] = *(const s16x8*)(_g + bOff[KH][3]);                                            \
  } while (0)

// stage one float4: exact stats + bf16 A + bf16 mask -> LDS (b64 each)
#define XFORM(v, BUF) do {                                                                \
    s1 += (double)v.x + (double)v.y + (double)v.z + (double)v.w;                          \
    cnt += (v.x > 0.f) + (v.y > 0.f) + (v.z > 0.f) + (v.w > 0.f);                         \
    unsigned dlo, dhi;                                                                    \
    asm("v_cvt_pk_bf16_f32 %0, %1, %2" : "=v"(dlo) : "v"(v.x), "v"(v.y));                 \
    asm("v_cvt_pk_bf16_f32 %0, %1, %2" : "=v"(dhi) : "v"(v.z), "v"(v.w));                 \
    unsigned mlo = (v.x > 0.f ? 0x3F80u : 0u) | (v.y > 0.f ? 0x3F800000u : 0u);           \
    unsigned mhi = (v.z > 0.f ? 0x3F80u : 0u) | (v.w > 0.f ? 0x3F800000u : 0u);           \
    *(unsigned long long*)((BUF) + aWr) =                                                 \
        (unsigned long long)dlo | ((unsigned long long)dhi << 32);                        \
    *(unsigned long long*)((BUF) + 4096 + aWr) =                                          \
        (unsigned long long)mlo | ((unsigned long long)mhi << 32);                        \
  } while (0)

// one kh half: 1 A-frag + 1 M-frag LDS read, 8 dual-MFMA with the given B set
#define MFMA_KH(BUF, KH, BS) do {                                                         \
    s16x8 af = *(const s16x8*)((BUF) + aOff[KH]);                                         \
    s16x8 mf = *(const s16x8*)((BUF) + 4096 + aOff[KH]);                                  \
    __builtin_amdgcn_s_setprio(1);                                                        \
    acc1[0] = MFMA_(af, BS[0], acc1[0], 0, 0, 0);                                         \
    acc2[0] = MFMA_(mf, BS[0], acc2[0], 0, 0, 0);                                         \
    acc1[1] = MFMA_(af, BS[1], acc1[1], 0, 0, 0);                                         \
    acc2[1] = MFMA_(mf, BS[1], acc2[1], 0, 0, 0);                                         \
    acc1[2] = MFMA_(af, BS[2], acc1[2], 0, 0, 0);                                         \
    acc2[2] = MFMA_(mf, BS[2], acc2[2], 0, 0, 0);                                         \
    acc1[3] = MFMA_(af, BS[3], acc1[3], 0, 0, 0);                                         \
    acc2[3] = MFMA_(mf, BS[3], acc2[3], 0, 0, 0);                                         \
    __builtin_amdgcn_s_setprio(0);                                                        \
  } while (0)

#define SYNC() do { FENCE(); WAITLGKM(); FENCE(); BARRIER(); FENCE(); } while (0)

  // ---- prologue ----
  ISSUE_A(x, 0);
  LOADB(bA, 0, 0);               // kh0 of tile 0
  ISSUE_A(y, 1);
  XFORM(x, buf0);                // compiler waits x precisely, leaves rest in flight
  SYNC();

  // ---- steady: tiles 0..125, unrolled by 2 ----
  for (int kt = 0; kt < 126; kt += 2) {
    // even tile kt (buf0)
    ISSUE_A(x, kt + 2);
    LOADB(bB, kt, 1);            // kh1 of current tile
    FENCE();
    MFMA_KH(buf0, 0, bA);        // kh0 (covers bB's L2 latency)
    LOADB(bA, kt + 1, 0);        // kh0 of next tile
    FENCE();
    MFMA_KH(buf0, 1, bB);        // kh1
    XFORM(y, buf1);
    SYNC();
    // odd tile kt+1 (buf1)
    ISSUE_A(y, kt + 3);
    LOADB(bB, kt + 1, 1);
    FENCE();
    MFMA_KH(buf1, 0, bA);
    LOADB(bA, kt + 2, 0);
    FENCE();
    MFMA_KH(buf1, 1, bB);
    XFORM(x, buf0);
    SYNC();
  }

  // ---- tail: tile 126 (buf0) ----
  LOADB(bB, 126, 1);
  FENCE();
  MFMA_KH(buf0, 0, bA);
  LOADB(bA, 127, 0);
  FENCE();
  MFMA_KH(buf0, 1, bB);
  XFORM(y, buf1);                // A(127)
  SYNC();
  // ---- tail: tile 127 (buf1) ----
  LOADB(bB, 127, 1);
  FENCE();
  MFMA_KH(buf1, 0, bA);
  FENCE();
  MFMA_KH(buf1, 1, bB);

  // ---- stats: reduce over sp (16 consecutive lanes share row sm) ----
#pragma unroll
  for (int o = 1; o < 16; o <<= 1) {
    s1 += __shfl_xor(s1, o);
    cnt += __shfl_xor(cnt, o);
  }
  __syncthreads();               // everyone past buf0 reads -> reuse as stats
  float* const invsS = (float*)buf0;    // 32 floats
  float* const rdegS = invsS + 32;      // 32 floats
  if (sp == 0) {
    double sq = sqrt((double)cnt);
    invsS[sm] = (cnt > 0) ? (float)(1.0 / sq) : 0.0f;
    rdegS[sm] = (float)(1.0 / (s1 + sq));
  }
  __syncthreads();

  // ---- epilogue: (acc1 + invs*acc2) * rdeg ----
#pragma unroll
  for (int cg = 0; cg < 4; ++cg) {
#pragma unroll
    for (int j = 0; j < 4; ++j) {
      int row = wr * 16 + q * 4 + j;
      out[(size_t)(brow + row) * DDIM + nt * 256 + wc * 64 + cg * 16 + r] =
          (acc1[cg][j] + invsS[row] * acc2[cg][j]) * rdegS[row];
    }
  }
#undef ISSUE_A
#undef LOADB
#undef XFORM
#undef MFMA_KH
#undef SYNC
}

extern "C" void kernel_launch(void* const* d_in, const int* in_sizes, int n_in,
                              void* d_out, int out_size, void* d_ws, size_t ws_size,
                              hipStream_t stream) {
  const float* cur = (const float*)d_in[0];          // [8192, 512] fp32
  const float* incm = (const float*)d_in[1];         // [8192, 8192] fp32
  float* out = (float*)d_out;                        // [8192, 512] fp32
  unsigned char* bws = (unsigned char*)d_ws;         // 8MB B chunks

  hipLaunchKernelGGL(bprep_kernel, dim3((NROWS * DDIM / 8) / 256), dim3(256), 0, stream,
                     cur, bws);
  hipLaunchKernelGGL(gemm_kernel, dim3(512), dim3(512), 0, stream, incm, bws, out);
}

// Round 14
// 176.097 us; speedup vs baseline: 1.3189x; 1.3189x over previous
//
#include <hip/hip_runtime.h>
#include <stdint.h>

// SpatialHyperedgeMP: out = ((inc + head) @ cur) / rowsum(inc + head)
//   head_ij = (inc_ij > 0) / sqrt(cnt_i),  cnt_i = #positives in row i
// Decomposition (single fused pass over inc):
//   out[i] = (inc@cur + invs_i * (mask@cur)) * rdeg_i
//   invs_i = 1/sqrt(cnt_i),  rdeg_i = 1/(s1_i + sqrt(cnt_i))
//
// R14 = R11 (best: 167us) with BARRIER FREQUENCY HALVED. R11 post-mortem:
//   period 3731 cyc/tile-pair vs pipe demands (DS 1730, MFMA 1242, HBM ~700)
//   -> ~2000 cyc is synchronization overhead from 128 per-tile barriers.
//   R12/R13 (DS-diet attempts) both regressed by adding latency-critical work.
//   Here: 4 A+M LDS buffers (32KB, still 2 blk/CU) -> one lgkm+barrier per
//   2 K-tiles; B ping-pong (bX/bY) and all numerics byte-identical to R11;
//   raw-A prefetch deepened to 4 statically-named float4 regs.
//
// ws usage: 8MB B chunks only.

#define NROWS 8192
#define DDIM  512

typedef float f32x4 __attribute__((ext_vector_type(4)));
typedef short s16x8 __attribute__((ext_vector_type(8)));

__device__ __forceinline__ unsigned short f2bf(float f) {
  union { float f; unsigned int u; } c; c.f = f;
  unsigned int u = c.u;
  unsigned int r = u + 0x7FFFu + ((u >> 16) & 1u);
  return (unsigned short)(r >> 16);
}

// ---------------- kernel 1: B prep (cur -> bf16 chunked-transposed) ----------------
// chunk layout: nt(2) x kt(128): 32KB chunk = [kg=8][nn=256][e=8] bf16
__global__ __launch_bounds__(256) void bprep_kernel(const float* __restrict__ cur,
                                                    unsigned char* __restrict__ bws) {
  int idx = blockIdx.x * 256 + threadIdx.x;  // 0..524287
  int n = idx & 511;
  int kg9 = idx >> 9;  // 0..1023
  int kt = kg9 >> 3;
  int kg = kg9 & 7;
  int k0 = kt * 64 + kg * 8;
  union { unsigned short h[8]; uint4 q; } u;
#pragma unroll
  for (int e = 0; e < 8; ++e)
    u.h[e] = f2bf(cur[(size_t)(k0 + e) * DDIM + n]);
  int nt = n >> 8, nn = n & 255;
  size_t off = ((size_t)(nt * 128 + kt) << 15) + ((size_t)kg << 12) + ((size_t)nn << 4);
  *(uint4*)(bws + off) = u.q;
}

// ---------------- kernel 2: fused stats + dual-GEMM ----------------
// BM=32 BN=256 BK=64, 512 thr = 8 waves (1M x 8N), wave tile 32x32.
// LDS (32KB): 4 buffers x {A 4KB + M 4KB}; sync per 2 tiles; stats reuse buf0.

#define FENCE() __builtin_amdgcn_sched_barrier(0)
#define BARRIER() __builtin_amdgcn_s_barrier()
#define WAITLGKM() asm volatile("s_waitcnt lgkmcnt(0)" ::: "memory")
#define MFMA_ __builtin_amdgcn_mfma_f32_16x16x32_bf16

__global__ __launch_bounds__(512, 4) void gemm_kernel(const float* __restrict__ inc,
                                                      const unsigned char* __restrict__ bws,
                                                      float* __restrict__ out) {
  __shared__ __align__(16) unsigned char smem[32768];
  unsigned char* const buf0 = smem;            // A @0, M @+4096 within each buffer
  unsigned char* const buf1 = smem + 8192;
  unsigned char* const buf2 = smem + 16384;
  unsigned char* const buf3 = smem + 24576;

  const int tid = threadIdx.x;
  const int lane = tid & 63;
  const int wv = tid >> 6;       // 0..7 column group
  const int r = lane & 15;
  const int q = lane >> 4;       // 0..3

  const int id = blockIdx.x;     // 0..511
  const int nt = (id & 7) >> 2;  // XCD half -> fixed 4MB B chunk per XCD L2
  const int mt = (id >> 3) * 4 + (id & 3);   // 0..255; partners id,id^4 adjacent
  const int brow = mt * 32;

  // ---- A staging ownership: thread -> (row sm, float4-slot sp) ----
  const int sm = tid >> 4;       // 0..31
  const int sp = tid & 15;       // 0..15 (k = sp*4..sp*4+3)
  const int kgw = sp >> 1, half = sp & 1;
  const float4* gAr = (const float4*)(inc + (size_t)(brow + sm) * NROWS) + sp;
  const int aWr = (kgw << 9) + ((sm ^ kgw) << 4) + (half << 3);

  // ---- A/M frag LDS offsets: frag(kh,rg): kg=kh*4+q, row=rg*16+r ----
  int aOff[2][2];
#pragma unroll
  for (int kh = 0; kh < 2; ++kh)
#pragma unroll
    for (int rg = 0; rg < 2; ++rg) {
      int kg = kh * 4 + q;
      int row = rg * 16 + r;
      aOff[kh][rg] = (kg << 9) + ((row ^ kg) << 4);
    }

  // ---- B frag ws offsets (within 32KB kt-chunk) ----
  const unsigned char* gB = bws + ((size_t)(nt * 128) << 15);
  int bOff[4];  // [kh*2+cg]
#pragma unroll
  for (int kh = 0; kh < 2; ++kh)
#pragma unroll
    for (int cg = 0; cg < 2; ++cg)
      bOff[kh * 2 + cg] = ((kh * 4 + q) << 12) + ((wv * 32 + cg * 16 + r) << 4);

  f32x4 acc1[2][2], acc2[2][2];
#pragma unroll
  for (int a = 0; a < 2; ++a)
#pragma unroll
    for (int b = 0; b < 2; ++b) {
      acc1[a][b] = (f32x4){0.f, 0.f, 0.f, 0.f};
      acc2[a][b] = (f32x4){0.f, 0.f, 0.f, 0.f};
    }

  double s1 = 0.0;
  int cnt = 0;
  float4 x0, y0, x1, y1;         // raw A prefetch, 4 deep (static names)
  s16x8 bX[4], bY[4];            // B ping-pong (R11 schedule)

#define ISSUE_A(d, KT) do { d = gAr[(KT) * 16]; } while (0)

#define LOADB(BS, KT) do {                                                                \
    const unsigned char* _g = gB + ((size_t)(KT) << 15);                                  \
    BS[0] = *(const s16x8*)(_g + bOff[0]);                                                \
    BS[1] = *(const s16x8*)(_g + bOff[1]);                                                \
    BS[2] = *(const s16x8*)(_g + bOff[2]);                                                \
    BS[3] = *(const s16x8*)(_g + bOff[3]);                                                \
  } while (0)

// stage one float4: exact stats + bf16 A + bf16 mask -> LDS (b64 each)
#define XFORM(v, BUF) do {                                                                \
    s1 += (double)v.x + (double)v.y + (double)v.z + (double)v.w;                          \
    cnt += (v.x > 0.f) + (v.y > 0.f) + (v.z > 0.f) + (v.w > 0.f);                         \
    unsigned dlo, dhi;                                                                    \
    asm("v_cvt_pk_bf16_f32 %0, %1, %2" : "=v"(dlo) : "v"(v.x), "v"(v.y));                 \
    asm("v_cvt_pk_bf16_f32 %0, %1, %2" : "=v"(dhi) : "v"(v.z), "v"(v.w));                 \
    unsigned mlo = (v.x > 0.f ? 0x3F80u : 0u) | (v.y > 0.f ? 0x3F800000u : 0u);           \
    unsigned mhi = (v.z > 0.f ? 0x3F80u : 0u) | (v.w > 0.f ? 0x3F800000u : 0u);           \
    *(unsigned long long*)((BUF) + aWr) =                                                 \
        (unsigned long long)dlo | ((unsigned long long)dhi << 32);                        \
    *(unsigned long long*)((BUF) + 4096 + aWr) =                                          \
        (unsigned long long)mlo | ((unsigned long long)mhi << 32);                        \
  } while (0)

#define MFMA_TILE(BUF, BS) do {                                                           \
    _Pragma("unroll")                                                                     \
    for (int kh = 0; kh < 2; ++kh) {                                                      \
      s16x8 af0 = *(const s16x8*)((BUF) + aOff[kh][0]);                                   \
      s16x8 af1 = *(const s16x8*)((BUF) + aOff[kh][1]);                                   \
      s16x8 mf0 = *(const s16x8*)((BUF) + 4096 + aOff[kh][0]);                            \
      s16x8 mf1 = *(const s16x8*)((BUF) + 4096 + aOff[kh][1]);                            \
      __builtin_amdgcn_s_setprio(1);                                                      \
      acc1[0][0] = MFMA_(af0, BS[kh * 2 + 0], acc1[0][0], 0, 0, 0);                       \
      acc2[0][0] = MFMA_(mf0, BS[kh * 2 + 0], acc2[0][0], 0, 0, 0);                       \
      acc1[0][1] = MFMA_(af0, BS[kh * 2 + 1], acc1[0][1], 0, 0, 0);                       \
      acc2[0][1] = MFMA_(mf0, BS[kh * 2 + 1], acc2[0][1], 0, 0, 0);                       \
      acc1[1][0] = MFMA_(af1, BS[kh * 2 + 0], acc1[1][0], 0, 0, 0);                       \
      acc2[1][0] = MFMA_(mf1, BS[kh * 2 + 0], acc2[1][0], 0, 0, 0);                       \
      acc1[1][1] = MFMA_(af1, BS[kh * 2 + 1], acc1[1][1], 0, 0, 0);                       \
      acc2[1][1] = MFMA_(mf1, BS[kh * 2 + 1], acc2[1][1], 0, 0, 0);                       \
      __builtin_amdgcn_s_setprio(0);                                                      \
    }                                                                                     \
  } while (0)

#define SYNC() do { FENCE(); WAITLGKM(); FENCE(); BARRIER(); FENCE(); } while (0)

  // ---- prologue: establish {buf0,buf1}=tiles 0,1; x1,y1=raw(2,3); bX=B(0) ----
  ISSUE_A(x0, 0);
  LOADB(bX, 0);
  ISSUE_A(y0, 1);
  ISSUE_A(x1, 2);
  ISSUE_A(y1, 3);
  XFORM(x0, buf0);
  XFORM(y0, buf1);
  SYNC();

  // ---- steady: 31 groups x 4 tiles, ONE sync per 2 tiles ----
  for (int i = 0; i < 31; ++i) {
    const int t = i * 4;
    // half A: MFMA tiles t,t+1 (buf0,buf1); stage t+2,t+3 (buf2,buf3)
    ISSUE_A(x0, t + 4);
    ISSUE_A(y0, t + 5);
    LOADB(bY, t + 1);
    FENCE();
    MFMA_TILE(buf0, bX);
    XFORM(x1, buf2);
    LOADB(bX, t + 2);
    FENCE();
    MFMA_TILE(buf1, bY);
    XFORM(y1, buf3);
    SYNC();
    // half B: MFMA tiles t+2,t+3 (buf2,buf3); stage t+4,t+5 (buf0,buf1)
    ISSUE_A(x1, t + 6);
    ISSUE_A(y1, t + 7);
    LOADB(bY, t + 3);
    FENCE();
    MFMA_TILE(buf2, bX);
    XFORM(x0, buf0);
    LOADB(bX, t + 4);
    FENCE();
    MFMA_TILE(buf3, bY);
    XFORM(y0, buf1);
    SYNC();
  }

  // ---- tail group 31: tiles 124..127 (x1,y1 = raw 126,127; bX = B(124)) ----
  LOADB(bY, 125);
  FENCE();
  MFMA_TILE(buf0, bX);   // tile 124
  XFORM(x1, buf2);       // stage 126
  LOADB(bX, 126);
  FENCE();
  MFMA_TILE(buf1, bY);   // tile 125
  XFORM(y1, buf3);       // stage 127
  SYNC();
  LOADB(bY, 127);
  FENCE();
  MFMA_TILE(buf2, bX);   // tile 126
  FENCE();
  MFMA_TILE(buf3, bY);   // tile 127

  // ---- stats: reduce over sp (16 consecutive lanes share row sm) ----
#pragma unroll
  for (int o = 1; o < 16; o <<= 1) {
    s1 += __shfl_xor(s1, o);
    cnt += __shfl_xor(cnt, o);
  }
  __syncthreads();               // everyone past buf0 reads -> reuse as stats
  float* const invsS = (float*)buf0;    // 32 floats
  float* const rdegS = invsS + 32;      // 32 floats
  if (sp == 0) {
    double sq = sqrt((double)cnt);
    invsS[sm] = (cnt > 0) ? (float)(1.0 / sq) : 0.0f;
    rdegS[sm] = (float)(1.0 / (s1 + sq));
  }
  __syncthreads();

  // ---- epilogue: (acc1 + invs*acc2) * rdeg ----
#pragma unroll
  for (int rg = 0; rg < 2; ++rg) {
#pragma unroll
    for (int cg = 0; cg < 2; ++cg) {
#pragma unroll
      for (int j = 0; j < 4; ++j) {
        int row = rg * 16 + q * 4 + j;
        out[(size_t)(brow + row) * DDIM + nt * 256 + wv * 32 + cg * 16 + r] =
            (acc1[rg][cg][j] + invsS[row] * acc2[rg][cg][j]) * rdegS[row];
      }
    }
  }
#undef ISSUE_A
#undef LOADB
#undef XFORM
#undef MFMA_TILE
#undef SYNC
}

extern "C" void kernel_launch(void* const* d_in, const int* in_sizes, int n_in,
                              void* d_out, int out_size, void* d_ws, size_t ws_size,
                              hipStream_t stream) {
  const float* cur = (const float*)d_in[0];          // [8192, 512] fp32
  const float* incm = (const float*)d_in[1];         // [8192, 8192] fp32
  float* out = (float*)d_out;                        // [8192, 512] fp32
  unsigned char* bws = (unsigned char*)d_ws;         // 8MB B chunks

  hipLaunchKernelGGL(bprep_kernel, dim3((NROWS * DDIM / 8) / 256), dim3(256), 0, stream,
                     cur, bws);
  hipLaunchKernelGGL(gemm_kernel, dim3(512), dim3(512), 0, stream, incm, bws, out);
}

// Round 15
// 172.488 us; speedup vs baseline: 1.3465x; 1.0209x over previous
//
#include <hip/hip_runtime.h>
#include <stdint.h>

// SpatialHyperedgeMP: out = ((inc + head) @ cur) / rowsum(inc + head)
//   head_ij = (inc_ij > 0) / sqrt(cnt_i),  cnt_i = #positives in row i
// Decomposition (single fused pass over inc):
//   out[i] = (inc@cur + invs_i * (mask@cur)) * rdeg_i
//   invs_i = 1/sqrt(cnt_i),  rdeg_i = 1/(s1_i + sqrt(cnt_i))
//
// R15 = R14 minus the spill. R14 post-mortem: 2-tile sync helped (gemm 199->190
//   profiled) but the 4-deep raw-A prefetch (+8 VGPR) spilled (WRITE 16.4->29.7MB)
//   and ate the gain. Here: prefetch back to 2 regs (x,y), A-issues ordered
//   BEFORE B-issues per half-group so compiler auto-vmcnt retires only the A
//   being consumed (B rides through). Everything else identical to R14:
//   4 A+M LDS buffers (32KB), one lgkm+barrier per 2 K-tiles, B bX/bY
//   full-tile ping-pong, R11 numerics/swizzles/grid (512 thr, 2 blk/CU).
//
// ws usage: 8MB B chunks only.

#define NROWS 8192
#define DDIM  512

typedef float f32x4 __attribute__((ext_vector_type(4)));
typedef short s16x8 __attribute__((ext_vector_type(8)));

__device__ __forceinline__ unsigned short f2bf(float f) {
  union { float f; unsigned int u; } c; c.f = f;
  unsigned int u = c.u;
  unsigned int r = u + 0x7FFFu + ((u >> 16) & 1u);
  return (unsigned short)(r >> 16);
}

// ---------------- kernel 1: B prep (cur -> bf16 chunked-transposed) ----------------
// chunk layout: nt(2) x kt(128): 32KB chunk = [kg=8][nn=256][e=8] bf16
__global__ __launch_bounds__(256) void bprep_kernel(const float* __restrict__ cur,
                                                    unsigned char* __restrict__ bws) {
  int idx = blockIdx.x * 256 + threadIdx.x;  // 0..524287
  int n = idx & 511;
  int kg9 = idx >> 9;  // 0..1023
  int kt = kg9 >> 3;
  int kg = kg9 & 7;
  int k0 = kt * 64 + kg * 8;
  union { unsigned short h[8]; uint4 q; } u;
#pragma unroll
  for (int e = 0; e < 8; ++e)
    u.h[e] = f2bf(cur[(size_t)(k0 + e) * DDIM + n]);
  int nt = n >> 8, nn = n & 255;
  size_t off = ((size_t)(nt * 128 + kt) << 15) + ((size_t)kg << 12) + ((size_t)nn << 4);
  *(uint4*)(bws + off) = u.q;
}

// ---------------- kernel 2: fused stats + dual-GEMM ----------------
// BM=32 BN=256 BK=64, 512 thr = 8 waves (1M x 8N), wave tile 32x32.
// LDS (32KB): 4 buffers x {A 4KB + M 4KB}; sync per 2 tiles; stats reuse buf0.

#define FENCE() __builtin_amdgcn_sched_barrier(0)
#define BARRIER() __builtin_amdgcn_s_barrier()
#define WAITLGKM() asm volatile("s_waitcnt lgkmcnt(0)" ::: "memory")
#define MFMA_ __builtin_amdgcn_mfma_f32_16x16x32_bf16

__global__ __launch_bounds__(512, 4) void gemm_kernel(const float* __restrict__ inc,
                                                      const unsigned char* __restrict__ bws,
                                                      float* __restrict__ out) {
  __shared__ __align__(16) unsigned char smem[32768];
  unsigned char* const buf0 = smem;            // A @0, M @+4096 within each buffer
  unsigned char* const buf1 = smem + 8192;
  unsigned char* const buf2 = smem + 16384;
  unsigned char* const buf3 = smem + 24576;

  const int tid = threadIdx.x;
  const int lane = tid & 63;
  const int wv = tid >> 6;       // 0..7 column group
  const int r = lane & 15;
  const int q = lane >> 4;       // 0..3

  const int id = blockIdx.x;     // 0..511
  const int nt = (id & 7) >> 2;  // XCD half -> fixed 4MB B chunk per XCD L2
  const int mt = (id >> 3) * 4 + (id & 3);   // 0..255; partners id,id^4 adjacent
  const int brow = mt * 32;

  // ---- A staging ownership: thread -> (row sm, float4-slot sp) ----
  const int sm = tid >> 4;       // 0..31
  const int sp = tid & 15;       // 0..15 (k = sp*4..sp*4+3)
  const int kgw = sp >> 1, half = sp & 1;
  const float4* gAr = (const float4*)(inc + (size_t)(brow + sm) * NROWS) + sp;
  const int aWr = (kgw << 9) + ((sm ^ kgw) << 4) + (half << 3);

  // ---- A/M frag LDS offsets: frag(kh,rg): kg=kh*4+q, row=rg*16+r ----
  int aOff[2][2];
#pragma unroll
  for (int kh = 0; kh < 2; ++kh)
#pragma unroll
    for (int rg = 0; rg < 2; ++rg) {
      int kg = kh * 4 + q;
      int row = rg * 16 + r;
      aOff[kh][rg] = (kg << 9) + ((row ^ kg) << 4);
    }

  // ---- B frag ws offsets (within 32KB kt-chunk) ----
  const unsigned char* gB = bws + ((size_t)(nt * 128) << 15);
  int bOff[4];  // [kh*2+cg]
#pragma unroll
  for (int kh = 0; kh < 2; ++kh)
#pragma unroll
    for (int cg = 0; cg < 2; ++cg)
      bOff[kh * 2 + cg] = ((kh * 4 + q) << 12) + ((wv * 32 + cg * 16 + r) << 4);

  f32x4 acc1[2][2], acc2[2][2];
#pragma unroll
  for (int a = 0; a < 2; ++a)
#pragma unroll
    for (int b = 0; b < 2; ++b) {
      acc1[a][b] = (f32x4){0.f, 0.f, 0.f, 0.f};
      acc2[a][b] = (f32x4){0.f, 0.f, 0.f, 0.f};
    }

  double s1 = 0.0;
  int cnt = 0;
  float4 x, y;                   // raw A prefetch, 2 deep (static names; no spill)
  s16x8 bX[4], bY[4];            // B ping-pong (R11 schedule)

#define ISSUE_A(d, KT) do { d = gAr[(KT) * 16]; } while (0)

#define LOADB(BS, KT) do {                                                                \
    const unsigned char* _g = gB + ((size_t)(KT) << 15);                                  \
    BS[0] = *(const s16x8*)(_g + bOff[0]);                                                \
    BS[1] = *(const s16x8*)(_g + bOff[1]);                                                \
    BS[2] = *(const s16x8*)(_g + bOff[2]);                                                \
    BS[3] = *(const s16x8*)(_g + bOff[3]);                                                \
  } while (0)

// stage one float4: exact stats + bf16 A + bf16 mask -> LDS (b64 each)
#define XFORM(v, BUF) do {                                                                \
    s1 += (double)v.x + (double)v.y + (double)v.z + (double)v.w;                          \
    cnt += (v.x > 0.f) + (v.y > 0.f) + (v.z > 0.f) + (v.w > 0.f);                         \
    unsigned dlo, dhi;                                                                    \
    asm("v_cvt_pk_bf16_f32 %0, %1, %2" : "=v"(dlo) : "v"(v.x), "v"(v.y));                 \
    asm("v_cvt_pk_bf16_f32 %0, %1, %2" : "=v"(dhi) : "v"(v.z), "v"(v.w));                 \
    unsigned mlo = (v.x > 0.f ? 0x3F80u : 0u) | (v.y > 0.f ? 0x3F800000u : 0u);           \
    unsigned mhi = (v.z > 0.f ? 0x3F80u : 0u) | (v.w > 0.f ? 0x3F800000u : 0u);           \
    *(unsigned long long*)((BUF) + aWr) =                                                 \
        (unsigned long long)dlo | ((unsigned long long)dhi << 32);                        \
    *(unsigned long long*)((BUF) + 4096 + aWr) =                                          \
        (unsigned long long)mlo | ((unsigned long long)mhi << 32);                        \
  } while (0)

#define MFMA_TILE(BUF, BS) do {                                                           \
    _Pragma("unroll")                                                                     \
    for (int kh = 0; kh < 2; ++kh) {                                                      \
      s16x8 af0 = *(const s16x8*)((BUF) + aOff[kh][0]);                                   \
      s16x8 af1 = *(const s16x8*)((BUF) + aOff[kh][1]);                                   \
      s16x8 mf0 = *(const s16x8*)((BUF) + 4096 + aOff[kh][0]);                            \
      s16x8 mf1 = *(const s16x8*)((BUF) + 4096 + aOff[kh][1]);                            \
      __builtin_amdgcn_s_setprio(1);                                                      \
      acc1[0][0] = MFMA_(af0, BS[kh * 2 + 0], acc1[0][0], 0, 0, 0);                       \
      acc2[0][0] = MFMA_(mf0, BS[kh * 2 + 0], acc2[0][0], 0, 0, 0);                       \
      acc1[0][1] = MFMA_(af0, BS[kh * 2 + 1], acc1[0][1], 0, 0, 0);                       \
      acc2[0][1] = MFMA_(mf0, BS[kh * 2 + 1], acc2[0][1], 0, 0, 0);                       \
      acc1[1][0] = MFMA_(af1, BS[kh * 2 + 0], acc1[1][0], 0, 0, 0);                       \
      acc2[1][0] = MFMA_(mf1, BS[kh * 2 + 0], acc2[1][0], 0, 0, 0);                       \
      acc1[1][1] = MFMA_(af1, BS[kh * 2 + 1], acc1[1][1], 0, 0, 0);                       \
      acc2[1][1] = MFMA_(mf1, BS[kh * 2 + 1], acc2[1][1], 0, 0, 0);                       \
      __builtin_amdgcn_s_setprio(0);                                                      \
    }                                                                                     \
  } while (0)

#define SYNC() do { FENCE(); WAITLGKM(); FENCE(); BARRIER(); FENCE(); } while (0)

  // ---- prologue: A-issues first (FIFO: x, y, then B -> auto-vmcnt retires A only)
  ISSUE_A(x, 0);
  ISSUE_A(y, 1);
  LOADB(bX, 0);
  XFORM(x, buf0);
  XFORM(y, buf1);
  SYNC();

  // ---- steady: 31 groups x 4 tiles, ONE sync per 2 tiles ----
  for (int i = 0; i < 31; ++i) {
    const int t = i * 4;
    // half A: MFMA tiles t,t+1 (buf0,buf1); stage t+2,t+3 (buf2,buf3)
    ISSUE_A(x, t + 2);
    ISSUE_A(y, t + 3);
    LOADB(bY, t + 1);
    FENCE();
    MFMA_TILE(buf0, bX);
    XFORM(x, buf2);
    LOADB(bX, t + 2);
    FENCE();
    MFMA_TILE(buf1, bY);
    XFORM(y, buf3);
    SYNC();
    // half B: MFMA tiles t+2,t+3 (buf2,buf3); stage t+4,t+5 (buf0,buf1)
    ISSUE_A(x, t + 4);
    ISSUE_A(y, t + 5);
    LOADB(bY, t + 3);
    FENCE();
    MFMA_TILE(buf2, bX);
    XFORM(x, buf0);
    LOADB(bX, t + 4);
    FENCE();
    MFMA_TILE(buf3, bY);
    XFORM(y, buf1);
    SYNC();
  }

  // ---- tail: tiles 124..127 (entering: buf0,buf1=124,125; bX=B(124)) ----
  ISSUE_A(x, 126);
  ISSUE_A(y, 127);
  LOADB(bY, 125);
  FENCE();
  MFMA_TILE(buf0, bX);   // tile 124
  XFORM(x, buf2);        // stage 126
  LOADB(bX, 126);
  FENCE();
  MFMA_TILE(buf1, bY);   // tile 125
  XFORM(y, buf3);        // stage 127
  SYNC();
  LOADB(bY, 127);
  FENCE();
  MFMA_TILE(buf2, bX);   // tile 126
  FENCE();
  MFMA_TILE(buf3, bY);   // tile 127

  // ---- stats: reduce over sp (16 consecutive lanes share row sm) ----
#pragma unroll
  for (int o = 1; o < 16; o <<= 1) {
    s1 += __shfl_xor(s1, o);
    cnt += __shfl_xor(cnt, o);
  }
  __syncthreads();               // everyone past buf0 reads -> reuse as stats
  float* const invsS = (float*)buf0;    // 32 floats
  float* const rdegS = invsS + 32;      // 32 floats
  if (sp == 0) {
    double sq = sqrt((double)cnt);
    invsS[sm] = (cnt > 0) ? (float)(1.0 / sq) : 0.0f;
    rdegS[sm] = (float)(1.0 / (s1 + sq));
  }
  __syncthreads();

  // ---- epilogue: (acc1 + invs*acc2) * rdeg ----
#pragma unroll
  for (int rg = 0; rg < 2; ++rg) {
#pragma unroll
    for (int cg = 0; cg < 2; ++cg) {
#pragma unroll
      for (int j = 0; j < 4; ++j) {
        int row = rg * 16 + q * 4 + j;
        out[(size_t)(brow + row) * DDIM + nt * 256 + wv * 32 + cg * 16 + r] =
            (acc1[rg][cg][j] + invsS[row] * acc2[rg][cg][j]) * rdegS[row];
      }
    }
  }
#undef ISSUE_A
#undef LOADB
#undef XFORM
#undef MFMA_TILE
#undef SYNC
}

extern "C" void kernel_launch(void* const* d_in, const int* in_sizes, int n_in,
                              void* d_out, int out_size, void* d_ws, size_t ws_size,
                              hipStream_t stream) {
  const float* cur = (const float*)d_in[0];          // [8192, 512] fp32
  const float* incm = (const float*)d_in[1];         // [8192, 8192] fp32
  float* out = (float*)d_out;                        // [8192, 512] fp32
  unsigned char* bws = (unsigned char*)d_ws;         // 8MB B chunks

  hipLaunchKernelGGL(bprep_kernel, dim3((NROWS * DDIM / 8) / 256), dim3(256), 0, stream,
                     cur, bws);
  hipLaunchKernelGGL(gemm_kernel, dim3(512), dim3(512), 0, stream, incm, bws, out);
}